// Round 25
// baseline (116.079 us; speedup 1.0000x reference)
//
#include <hip/hip_runtime.h>
#include <hip/hip_bf16.h>
#include <math.h>

// GateFusion via bf16 MFMA (16x16x32). r23 proven kernel (115.0us) + T14
// split-barrier staging: stage only phase-1 frags (20KB) before barrier-1;
// after it, ISSUE the 40KB phase-2 frag loads into registers, run phase-1
// MFMA+LN while they fly, ds_write them (write-late), barrier-2, phase 2.
// Hides the phase-2 staging latency under phase-1 compute.
// 32-row waves are CLOSED: r21/r24 both failed with identical absmax
// 1.578125 when the scratch-transpose epilogue ran twice per wave
// (mechanism not understood; single-use epilogue is proven r18/r22/r23).
// out = g * (x_d@W_d) + (1-g) * (x_c@W_c),
// g = sigmoid( relu(LN(concat@Wg1)) @ Wg2 ),  per row.
//
// d_ws: fragment-linear bf16 weights; lane l of frag holds B[k(l,j)][n],
//   n = nt*16 + (l&15),  k(l,j) = ks*32 + (j>>2)*16 + (l>>4)*4 + (j&3)
// (coalesced-load k-map; identical permutation in A and B operands cancels).

namespace {

typedef __attribute__((ext_vector_type(8))) short short8;
typedef __attribute__((ext_vector_type(4))) float f32x4;

constexpr int CD = 64, CC = 96, CH = 64, CF = 128;
constexpr int NFG1 = 20;   // gate-weight frags (staged pre-barrier-1)
constexpr int NFCB = 40;   // output-weight frags (issue-early/write-late)
constexpr int NFRAG = NFG1 + NFCB;
constexpr int CH1 = NFG1 * 512 * 2 / 16;      // 1280 16B chunks (gate frags)
constexpr int CH2 = NFCB * 512 * 2 / 16;      // 2560 16B chunks (out frags)

__device__ inline short bf16_of(float f) {
  __hip_bfloat16 h = __float2bfloat16(f);
  return *reinterpret_cast<short*>(&h);
}

__global__ void convert_weights(const float* __restrict__ Wd,
                                const float* __restrict__ Wc,
                                const float* __restrict__ Wg1,
                                short* __restrict__ ws) {
  const int t = blockIdx.x * 256 + threadIdx.x;
  if (t >= 64 * NFRAG) return;
  const int frag = t >> 6, l = t & 63;
  const int cidx = l & 15, kb = l >> 4;
  float v[8];
  if (frag < NFG1) {
    const int ks = frag >> 2, nt = frag & 3;
    const int n = nt * 16 + cidx;
    #pragma unroll
    for (int j = 0; j < 8; ++j) {
      const int k = ks * 32 + (j >> 2) * 16 + kb * 4 + (j & 3);
      v[j] = Wg1[k * CH + n];
    }
  } else {
    const int f2 = frag - NFG1;
    const int ks = f2 >> 3, nt = f2 & 7;
    const int n = nt * 16 + cidx;
    #pragma unroll
    for (int j = 0; j < 8; ++j) {
      const int k = ks * 32 + (j >> 2) * 16 + kb * 4 + (j & 3);
      v[j] = (k < CD) ? Wd[k * CF + n] : Wc[(k - CD) * CF + n];
    }
  }
  short8 o;
  #pragma unroll
  for (int j = 0; j < 8; ++j) o[j] = bf16_of(v[j]);
  *reinterpret_cast<short8*>(ws + frag * 512 + l * 8) = o;
}

__global__ __launch_bounds__(512, 2)
void gate_fusion_mfma(const float* __restrict__ xd,
                      const float* __restrict__ xc,
                      const float* __restrict__ gma,
                      const float* __restrict__ bta,
                      const float* __restrict__ Wg2,
                      const short* __restrict__ wf,
                      float* __restrict__ out, int N) {
  __shared__ short wlds[NFRAG * 512];    // 61440 B
  __shared__ float tr[8][4][136];        // 17408 B: transpose scratch

  const int tid  = threadIdx.x;
  const int lane = tid & 63;
  const int wv   = tid >> 6;                 // 0..7
  const int r0   = blockIdx.x * 128 + wv * 16;   // 16 rows per wave
  const int cidx = lane & 15;
  const int kb   = lane >> 4;
  const bool active = (r0 < N);              // wave-uniform (N % 16 == 0)

  const f32x4 vzero = {0.f, 0.f, 0.f, 0.f};

  // ---- x loads (coalesced 64B/4-lane segments, r14 k-map); inactive waves
  // get zeros (they run the compute harmlessly to reach barrier-2).
  f32x4 buf[5][2];
  #pragma unroll
  for (int ks = 0; ks < 5; ++ks) { buf[ks][0] = vzero; buf[ks][1] = vzero; }
  if (active) {
    const size_t row = (size_t)(r0 + cidx);
    const float* rd = xd + row * CD + kb * 4;
    const float* rc = xc + row * CC + kb * 4;
    #pragma unroll
    for (int ks = 0; ks < 5; ++ks) {
      const float* p = (ks < 2) ? (rd + ks * 32) : (rc + (ks - 2) * 32);
      buf[ks][0] = *reinterpret_cast<const f32x4*>(p);
      buf[ks][1] = *reinterpret_cast<const f32x4*>(p + 16);
    }
  }

  // ---- stage-1: gate frags only (1280 chunks = 20480 B)
  #pragma unroll
  for (int it = 0; it < 3; ++it) {
    const int c = tid + it * 512;
    if (it < 2 || c < CH1) {
      short8 v = *reinterpret_cast<const short8*>(wf + (size_t)c * 8);
      *reinterpret_cast<short8*>(&wlds[c * 8]) = v;
    }
  }
  __syncthreads();   // barrier-1: gate frags + x loads ready

  // ---- issue-early: phase-2 frag loads into registers (fly under phase-1)
  short8 w2r[5];
  #pragma unroll
  for (int it = 0; it < 5; ++it)
    w2r[it] = *reinterpret_cast<const short8*>(
        wf + (size_t)(CH1 + tid + it * 512) * 8);

  // per-wave constants (cache-hit loads)
  float gmv[4], btv[4], w2v[4];
  #pragma unroll
  for (int nt = 0; nt < 4; ++nt) {
    const int c = nt * 16 + cidx;
    gmv[nt] = gma[c]; btv[nt] = bta[c]; w2v[nt] = Wg2[c];
  }

  // ---- convert x to bf16 A-fragments
  short8 xf[5];
  #pragma unroll
  for (int ks = 0; ks < 5; ++ks) {
    short8 f;
    #pragma unroll
    for (int j = 0; j < 4; ++j) {
      f[j]     = bf16_of(buf[ks][0][j]);
      f[4 + j] = bf16_of(buf[ks][1][j]);
    }
    xf[ks] = f;
  }

  // ---- phase 1: h = x @ Wg1  [16 x 64]  (B-frags from LDS gate region)
  f32x4 acc1[4];
  #pragma unroll
  for (int nt = 0; nt < 4; ++nt) acc1[nt] = vzero;

  #pragma unroll
  for (int ks = 0; ks < 5; ++ks) {
    short8 bg[4];
    #pragma unroll
    for (int nt = 0; nt < 4; ++nt)
      bg[nt] = *reinterpret_cast<const short8*>(
          &wlds[(ks * 4 + nt) * 512 + lane * 8]);
    #pragma unroll
    for (int nt = 0; nt < 4; ++nt)
      acc1[nt] = __builtin_amdgcn_mfma_f32_16x16x32_bf16(
          xf[ks], bg[nt], acc1[nt], 0, 0, 0);
  }

  // ---- write-late: phase-2 frags into LDS (loads have been flying)
  #pragma unroll
  for (int it = 0; it < 5; ++it)
    *reinterpret_cast<short8*>(&wlds[((size_t)CH1 + tid + it * 512) * 8]) =
        w2r[it];

  // ---- LayerNorm + relu + dot(Wg2) + sigmoid (C-fragment layout)
  float gate[4];
  {
    float s[4], q[4];
    #pragma unroll
    for (int r = 0; r < 4; ++r) {
      s[r] = 0.f; q[r] = 0.f;
      #pragma unroll
      for (int nt = 0; nt < 4; ++nt) {
        const float c = acc1[nt][r];
        s[r] += c; q[r] += c * c;
      }
    }
    #pragma unroll
    for (int m = 1; m < 16; m <<= 1)
      #pragma unroll
      for (int r = 0; r < 4; ++r) {
        s[r] += __shfl_xor(s[r], m, 64);
        q[r] += __shfl_xor(q[r], m, 64);
      }
    float p[4];
    #pragma unroll
    for (int r = 0; r < 4; ++r) {
      const float mu  = s[r] * (1.f / CH);
      const float var = q[r] * (1.f / CH) - mu * mu;
      const float rsd = rsqrtf(var + 1e-5f);
      float pp = 0.f;
      #pragma unroll
      for (int nt = 0; nt < 4; ++nt) {
        const float h = fmaxf((acc1[nt][r] - mu) * rsd * gmv[nt] + btv[nt], 0.f);
        pp += h * w2v[nt];
      }
      p[r] = pp;
    }
    #pragma unroll
    for (int m = 1; m < 16; m <<= 1)
      #pragma unroll
      for (int r = 0; r < 4; ++r) p[r] += __shfl_xor(p[r], m, 64);
    #pragma unroll
    for (int r = 0; r < 4; ++r) gate[r] = 1.f / (1.f + expf(-p[r]));
  }

  __syncthreads();   // barrier-2: phase-2 frags visible to all waves
  if (!active) return;   // after BOTH barriers (no barrier divergence)

  // ---- phase 2: all 4 nt-quarter slices, blended results kept in registers
  f32x4 o[4][2];
  #pragma unroll
  for (int q = 0; q < 4; ++q) {
    f32x4 aD[2], aC[2];
    #pragma unroll
    for (int nt = 0; nt < 2; ++nt) { aD[nt] = vzero; aC[nt] = vzero; }

    #pragma unroll
    for (int ks = 0; ks < 5; ++ks) {
      short8 bg[2];
      #pragma unroll
      for (int nt = 0; nt < 2; ++nt)
        bg[nt] = *reinterpret_cast<const short8*>(
            &wlds[(NFG1 + ks * 8 + q * 2 + nt) * 512 + lane * 8]);
      if (ks < 2) {
        #pragma unroll
        for (int nt = 0; nt < 2; ++nt)
          aD[nt] = __builtin_amdgcn_mfma_f32_16x16x32_bf16(
              xf[ks], bg[nt], aD[nt], 0, 0, 0);
      } else {
        #pragma unroll
        for (int nt = 0; nt < 2; ++nt)
          aC[nt] = __builtin_amdgcn_mfma_f32_16x16x32_bf16(
              xf[ks], bg[nt], aC[nt], 0, 0, 0);
      }
    }
    #pragma unroll
    for (int nt = 0; nt < 2; ++nt)
      #pragma unroll
      for (int r = 0; r < 4; ++r)
        o[q][nt][r] = fmaf(gate[r], aD[nt][r] - aC[nt][r], aC[nt][r]);
  }

  // ---- transpose via per-wave LDS scratch + wide NT stores (512B runs)
  {
    float (*trw)[136] = tr[wv];
    #pragma unroll
    for (int r = 0; r < 4; ++r) {
      #pragma unroll
      for (int q = 0; q < 4; ++q)
        #pragma unroll
        for (int nt = 0; nt < 2; ++nt)
          trw[kb][(q * 2 + nt) * 16 + cidx] = o[q][nt][r];
      #pragma unroll
      for (int i = 0; i < 2; ++i) {
        const int ri = i * 2 + (lane >> 5);          // scratch row 0..3
        const f32x4 v = *reinterpret_cast<const f32x4*>(
            &trw[ri][(lane & 31) * 4]);
        float* dst = &out[((size_t)r0 + ri * 4 + r) * CF + (lane & 31) * 4];
        asm volatile("global_store_dwordx4 %0, %1, off nt"
                     :: "v"(dst), "v"(v) : "memory");
      }
    }
  }
}

}  // namespace

extern "C" void kernel_launch(void* const* d_in, const int* in_sizes, int n_in,
                              void* d_out, int out_size, void* d_ws, size_t ws_size,
                              hipStream_t stream) {
  const float* xd  = (const float*)d_in[0];
  const float* xc  = (const float*)d_in[1];
  const float* Wd  = (const float*)d_in[2];
  const float* Wc  = (const float*)d_in[3];
  const float* Wg1 = (const float*)d_in[4];
  const float* gma = (const float*)d_in[5];
  const float* bta = (const float*)d_in[6];
  const float* Wg2 = (const float*)d_in[7];
  float* out = (float*)d_out;
  short* ws  = (short*)d_ws;   // needs 60 KB

  const int N = in_sizes[0] / CD;

  convert_weights<<<dim3(15), dim3(256), 0, stream>>>(Wd, Wc, Wg1, ws);

  const int nblk = (N + 127) / 128;   // 128 rows per 8-wave block
  gate_fusion_mfma<<<dim3(nblk), dim3(512), 0, stream>>>(
      xd, xc, gma, bta, Wg2, ws, out, N);
}

// Round 26
// 114.332 us; speedup vs baseline: 1.0153x; 1.0153x over previous
//
#include <hip/hip_runtime.h>
#include <hip/hip_bf16.h>
#include <math.h>

// GateFusion via bf16 MFMA (16x16x32). TERMINAL configuration = r23 proven
// kernel (115.0us): one-shot 8-wave blocks, ALL 60 weight frags staged in
// LDS (removes every exposed L2 latency chain from the MFMA critical path),
// coalesced x-load burst, LDS-transpose epilogue + 512B-contiguous NT
// stores (NT needs >=512B contiguity: r20), exact HBM traffic
// (FETCH 156.5MB / WRITE 250MB).
// Session ledger: cross-tile load/compute overlap -- the only lever that
// would close the remaining 1.8x to the 64us BW floor -- is unavailable:
// source prefetch spills (r3/4/6), DMA over-fetches (r10), asm pipelines
// are either barrier-drained (r17) or corrupt under regalloc (r21/r24),
// split-barrier T14 is null (r25). Both real wins (NT wide stores r18,
// full LDS weight staging r23) removed serial latency; none remains.
// out = g * (x_d@W_d) + (1-g) * (x_c@W_c),
// g = sigmoid( relu(LN(concat@Wg1)) @ Wg2 ),  per row.
//
// d_ws: fragment-linear bf16 weights; lane l of frag holds B[k(l,j)][n],
//   n = nt*16 + (l&15),  k(l,j) = ks*32 + (j>>2)*16 + (l>>4)*4 + (j&3)
// (coalesced-load k-map; identical permutation in A and B operands cancels).

namespace {

typedef __attribute__((ext_vector_type(8))) short short8;
typedef __attribute__((ext_vector_type(4))) float f32x4;

constexpr int CD = 64, CC = 96, CH = 64, CF = 128;
constexpr int NFG1 = 20;   // gate-weight frags
constexpr int NFCB = 40;   // output-weight frags
constexpr int NFRAG = NFG1 + NFCB;            // 60 frags = 61440 B
constexpr int WCH_ALL = NFRAG * 512 * 2 / 16; // 3840 x 16B

__device__ inline short bf16_of(float f) {
  __hip_bfloat16 h = __float2bfloat16(f);
  return *reinterpret_cast<short*>(&h);
}

__global__ void convert_weights(const float* __restrict__ Wd,
                                const float* __restrict__ Wc,
                                const float* __restrict__ Wg1,
                                short* __restrict__ ws) {
  const int t = blockIdx.x * 256 + threadIdx.x;
  if (t >= 64 * NFRAG) return;
  const int frag = t >> 6, l = t & 63;
  const int cidx = l & 15, kb = l >> 4;
  float v[8];
  if (frag < NFG1) {
    const int ks = frag >> 2, nt = frag & 3;
    const int n = nt * 16 + cidx;
    #pragma unroll
    for (int j = 0; j < 8; ++j) {
      const int k = ks * 32 + (j >> 2) * 16 + kb * 4 + (j & 3);
      v[j] = Wg1[k * CH + n];
    }
  } else {
    const int f2 = frag - NFG1;
    const int ks = f2 >> 3, nt = f2 & 7;
    const int n = nt * 16 + cidx;
    #pragma unroll
    for (int j = 0; j < 8; ++j) {
      const int k = ks * 32 + (j >> 2) * 16 + kb * 4 + (j & 3);
      v[j] = (k < CD) ? Wd[k * CF + n] : Wc[(k - CD) * CF + n];
    }
  }
  short8 o;
  #pragma unroll
  for (int j = 0; j < 8; ++j) o[j] = bf16_of(v[j]);
  *reinterpret_cast<short8*>(ws + frag * 512 + l * 8) = o;
}

__global__ __launch_bounds__(512, 2)
void gate_fusion_mfma(const float* __restrict__ xd,
                      const float* __restrict__ xc,
                      const float* __restrict__ gma,
                      const float* __restrict__ bta,
                      const float* __restrict__ Wg2,
                      const short* __restrict__ wf,
                      float* __restrict__ out, int N) {
  __shared__ short wlds[NFRAG * 512];    // 61440 B: ALL 60 weight frags
  __shared__ float tr[8][4][136];        // 17408 B: padded transpose scratch

  const int tid  = threadIdx.x;
  const int lane = tid & 63;
  const int wv   = tid >> 6;                 // 0..7
  const int r0   = blockIdx.x * 128 + wv * 16;   // 16 rows per wave
  const int cidx = lane & 15;
  const int kb   = lane >> 4;
  const bool active = (r0 < N);              // wave-uniform (N % 16 == 0)

  // ---- x loads (coalesced 64B/4-lane segments, r14 k-map)
  f32x4 buf[5][2];
  if (active) {
    const size_t row = (size_t)(r0 + cidx);
    const float* rd = xd + row * CD + kb * 4;
    const float* rc = xc + row * CC + kb * 4;
    #pragma unroll
    for (int ks = 0; ks < 5; ++ks) {
      const float* p = (ks < 2) ? (rd + ks * 32) : (rc + (ks - 2) * 32);
      buf[ks][0] = *reinterpret_cast<const f32x4*>(p);
      buf[ks][1] = *reinterpret_cast<const f32x4*>(p + 16);
    }
  }

  // ---- stage all 60 weight frags (61440 B) into LDS
  {
    #pragma unroll
    for (int it = 0; it < 8; ++it) {
      const int c = tid + it * 512;
      if (it < 7 || c < WCH_ALL) {
        short8 v = *reinterpret_cast<const short8*>(wf + (size_t)c * 8);
        *reinterpret_cast<short8*>(&wlds[c * 8]) = v;
      }
    }
  }

  __syncthreads();
  if (!active) return;   // after the only barrier

  // per-wave constants (cache-hit loads)
  float gmv[4], btv[4], w2v[4];
  #pragma unroll
  for (int nt = 0; nt < 4; ++nt) {
    const int c = nt * 16 + cidx;
    gmv[nt] = gma[c]; btv[nt] = bta[c]; w2v[nt] = Wg2[c];
  }

  // ---- convert x to bf16 A-fragments
  short8 xf[5];
  #pragma unroll
  for (int ks = 0; ks < 5; ++ks) {
    short8 f;
    #pragma unroll
    for (int j = 0; j < 4; ++j) {
      f[j]     = bf16_of(buf[ks][0][j]);
      f[4 + j] = bf16_of(buf[ks][1][j]);
    }
    xf[ks] = f;
  }

  // ---- phase 1: h = x @ Wg1  [16 x 64]  (B-frags from LDS)
  const f32x4 vzero = {0.f, 0.f, 0.f, 0.f};
  f32x4 acc1[4];
  #pragma unroll
  for (int nt = 0; nt < 4; ++nt) acc1[nt] = vzero;

  #pragma unroll
  for (int ks = 0; ks < 5; ++ks) {
    short8 bg[4];
    #pragma unroll
    for (int nt = 0; nt < 4; ++nt)
      bg[nt] = *reinterpret_cast<const short8*>(
          &wlds[(ks * 4 + nt) * 512 + lane * 8]);
    #pragma unroll
    for (int nt = 0; nt < 4; ++nt)
      acc1[nt] = __builtin_amdgcn_mfma_f32_16x16x32_bf16(
          xf[ks], bg[nt], acc1[nt], 0, 0, 0);
  }

  // ---- LayerNorm + relu + dot(Wg2) + sigmoid (C-fragment layout)
  float gate[4];
  {
    float s[4], q[4];
    #pragma unroll
    for (int r = 0; r < 4; ++r) {
      s[r] = 0.f; q[r] = 0.f;
      #pragma unroll
      for (int nt = 0; nt < 4; ++nt) {
        const float c = acc1[nt][r];
        s[r] += c; q[r] += c * c;
      }
    }
    #pragma unroll
    for (int m = 1; m < 16; m <<= 1)
      #pragma unroll
      for (int r = 0; r < 4; ++r) {
        s[r] += __shfl_xor(s[r], m, 64);
        q[r] += __shfl_xor(q[r], m, 64);
      }
    float p[4];
    #pragma unroll
    for (int r = 0; r < 4; ++r) {
      const float mu  = s[r] * (1.f / CH);
      const float var = q[r] * (1.f / CH) - mu * mu;
      const float rsd = rsqrtf(var + 1e-5f);
      float pp = 0.f;
      #pragma unroll
      for (int nt = 0; nt < 4; ++nt) {
        const float h = fmaxf((acc1[nt][r] - mu) * rsd * gmv[nt] + btv[nt], 0.f);
        pp += h * w2v[nt];
      }
      p[r] = pp;
    }
    #pragma unroll
    for (int m = 1; m < 16; m <<= 1)
      #pragma unroll
      for (int r = 0; r < 4; ++r) p[r] += __shfl_xor(p[r], m, 64);
    #pragma unroll
    for (int r = 0; r < 4; ++r) gate[r] = 1.f / (1.f + expf(-p[r]));
  }

  // ---- phase 2: all 4 nt-quarter slices, blended results kept in registers
  f32x4 o[4][2];
  #pragma unroll
  for (int q = 0; q < 4; ++q) {
    f32x4 aD[2], aC[2];
    #pragma unroll
    for (int nt = 0; nt < 2; ++nt) { aD[nt] = vzero; aC[nt] = vzero; }

    #pragma unroll
    for (int ks = 0; ks < 5; ++ks) {
      short8 bg[2];
      #pragma unroll
      for (int nt = 0; nt < 2; ++nt)
        bg[nt] = *reinterpret_cast<const short8*>(
            &wlds[(NFG1 + ks * 8 + q * 2 + nt) * 512 + lane * 8]);
      if (ks < 2) {
        #pragma unroll
        for (int nt = 0; nt < 2; ++nt)
          aD[nt] = __builtin_amdgcn_mfma_f32_16x16x32_bf16(
              xf[ks], bg[nt], aD[nt], 0, 0, 0);
      } else {
        #pragma unroll
        for (int nt = 0; nt < 2; ++nt)
          aC[nt] = __builtin_amdgcn_mfma_f32_16x16x32_bf16(
              xf[ks], bg[nt], aC[nt], 0, 0, 0);
      }
    }
    #pragma unroll
    for (int nt = 0; nt < 2; ++nt)
      #pragma unroll
      for (int r = 0; r < 4; ++r)
        o[q][nt][r] = fmaf(gate[r], aD[nt][r] - aC[nt][r], aC[nt][r]);
  }

  // ---- transpose via per-wave LDS scratch + wide NT stores (512B runs)
  {
    float (*trw)[136] = tr[wv];
    #pragma unroll
    for (int r = 0; r < 4; ++r) {
      #pragma unroll
      for (int q = 0; q < 4; ++q)
        #pragma unroll
        for (int nt = 0; nt < 2; ++nt)
          trw[kb][(q * 2 + nt) * 16 + cidx] = o[q][nt][r];
      #pragma unroll
      for (int i = 0; i < 2; ++i) {
        const int ri = i * 2 + (lane >> 5);          // scratch row 0..3
        const f32x4 v = *reinterpret_cast<const f32x4*>(
            &trw[ri][(lane & 31) * 4]);
        float* dst = &out[((size_t)r0 + ri * 4 + r) * CF + (lane & 31) * 4];
        asm volatile("global_store_dwordx4 %0, %1, off nt"
                     :: "v"(dst), "v"(v) : "memory");
      }
    }
  }
}

}  // namespace

extern "C" void kernel_launch(void* const* d_in, const int* in_sizes, int n_in,
                              void* d_out, int out_size, void* d_ws, size_t ws_size,
                              hipStream_t stream) {
  const float* xd  = (const float*)d_in[0];
  const float* xc  = (const float*)d_in[1];
  const float* Wd  = (const float*)d_in[2];
  const float* Wc  = (const float*)d_in[3];
  const float* Wg1 = (const float*)d_in[4];
  const float* gma = (const float*)d_in[5];
  const float* bta = (const float*)d_in[6];
  const float* Wg2 = (const float*)d_in[7];
  float* out = (float*)d_out;
  short* ws  = (short*)d_ws;   // needs 60 KB

  const int N = in_sizes[0] / CD;

  convert_weights<<<dim3(15), dim3(256), 0, stream>>>(Wd, Wc, Wg1, ws);

  const int nblk = (N + 127) / 128;   // 128 rows per 8-wave block
  gate_fusion_mfma<<<dim3(nblk), dim3(512), 0, stream>>>(
      xd, xc, gma, bta, Wg2, ws, out, N);
}